// Round 8
// baseline (498.906 us; speedup 1.0000x reference)
//
#include <hip/hip_runtime.h>

typedef __bf16 bf16;
typedef __bf16 bf16x4 __attribute__((ext_vector_type(4)));
typedef __bf16 bf16x8 __attribute__((ext_vector_type(8)));
typedef float f32x4 __attribute__((ext_vector_type(4)));

#define MFMA(a, b, c) __builtin_amdgcn_mfma_f32_16x16x32_bf16(a, b, c, 0, 0, 0)

__device__ __forceinline__ float fast_silu(float x) {
  float e = __builtin_amdgcn_exp2f(x * -1.4426950408889634f);
  return x * __builtin_amdgcn_rcpf(1.f + e);
}

// async global->LDS, 16B/lane. LDS dest must be wave-uniform base + lane*16;
// all swizzling goes on the GLOBAL address.
__device__ __forceinline__ void gload_lds16(const void* g, void* l) {
  __builtin_amdgcn_global_load_lds(
      (const __attribute__((address_space(1))) void*)g,
      (__attribute__((address_space(3))) void*)l, 16, 0, 0);
}

// ---------------------------------------------------------------------------
__global__ __launch_bounds__(256) void cvt_bf16(const float* __restrict__ in,
                                                bf16* __restrict__ out, int n) {
  int i = (blockIdx.x * 256 + threadIdx.x) * 4;
  if (i >= n) return;
  float4 v = *(const float4*)(in + i);
  bf16x4 o = {(bf16)v.x, (bf16)v.y, (bf16)v.z, (bf16)v.w};
  *(bf16x4*)(out + i) = o;
}

// v_weight [4096,2048] fp32 -> vt [2048,4096] bf16 (vt[hd][m] = v[m][hd]).
__global__ __launch_bounds__(256) void transpose_v_cvt(const float* __restrict__ v,
                                                       bf16* __restrict__ vt) {
  __shared__ bf16 T[64 * 72];
  const int m0 = blockIdx.x * 64, c0 = blockIdx.y * 64;
  const int tid = threadIdx.x;
  const int tr = tid >> 3;        // 0..31
  const int tc = (tid & 7) << 3;  // 0..56
#pragma unroll
  for (int it = 0; it < 2; it++) {
    int r = tr + it * 32;
    const float* src = v + (long)(m0 + r) * 2048 + c0 + tc;
    float4 a = *(const float4*)src;
    float4 b = *(const float4*)(src + 4);
    bf16x8 t = {(bf16)a.x, (bf16)a.y, (bf16)a.z, (bf16)a.w,
                (bf16)b.x, (bf16)b.y, (bf16)b.z, (bf16)b.w};
    *(bf16x8*)&T[r * 72 + tc] = t;
  }
  __syncthreads();
#pragma unroll
  for (int it = 0; it < 2; it++) {
    int c = tr + it * 32;
    bf16x8 o;
#pragma unroll
    for (int j = 0; j < 8; j++) o[j] = T[(tc + j) * 72 + c];
    *(bf16x8*)(vt + (long)(c0 + c) * 4096 + m0 + tc) = o;
  }
}

// ---------------------------------------------------------------------------
// NT GEMM, BM x 256 tile, BK=64, 512 threads (8 waves, 2M x 4N), 4-phase
// interleaved K-loop (round-5 best-measured variant):
//   per phase: {ds_read frags || stage 2 gload_lds of tile t+1} -> s_barrier
//              -> setprio(1) 16 MFMA setprio(0) -> s_barrier
//   one __syncthreads (vmcnt drain) per K-tile.
// LDS [row][64] bf16, 16B-block swizzle blk ^= row&7 (conflict-free ds_read,
// pre-swizzled global source for the linear gload_lds dest — rule 21).
// MODE 3 (BM=256): dual-output, gx<8 -> C1 = qscale*(A B^T), gx>=8 ->
//   C2 = silu(A B2^T). grid 256 flat.   MODE 2 (BM=128): Cf = A B^T (fp32).
// XCD-bijective block swizzle (grid 256 % 8 == 0).
// ---------------------------------------------------------------------------
template <int MODE, int BM>
__global__ __launch_bounds__(512, 2) void gemm256(const bf16* __restrict__ A,
                                                  const bf16* __restrict__ B,
                                                  const bf16* __restrict__ B2,
                                                  bf16* __restrict__ C1,
                                                  bf16* __restrict__ C2,
                                                  float* __restrict__ Cf, int K, int N) {
  constexpr int MR = BM / 32;  // 16-row A-frags per wave
  constexpr int MR2 = MR / 2;
  constexpr int NA = BM / 64;  // A stage instrs per K-tile (64 rows each)
  __shared__ bf16 As[2][BM * 64];
  __shared__ bf16 Bs[2][256 * 64];

  const int tid = threadIdx.x, wave = tid >> 6, lane = tid & 63;
  const int wr = wave >> 2, wc = wave & 3;
  const int quad = lane >> 4, fr = lane & 15;

  // XCD-bijective swizzle: 32 consecutive ids (one XCD) share one B-panel.
  const int id2 = (blockIdx.x & 7) * 32 + (blockIdx.x >> 3);
  const int gx = (MODE == 3) ? (id2 >> 4) : (id2 >> 5);
  const int gy = (MODE == 3) ? (id2 & 15) : (id2 & 31);
  const bool gsel = (MODE == 3) && (gx >= 8);
  const bf16* Bm = gsel ? B2 : B;
  const long bM = (long)gy * BM;
  const long bN = (long)((MODE == 3) ? (gx & 7) : gx) * 256;

  f32x4 acc[MR][4] = {};

  // Staging: thread t writes LDS bytes [t*16, +16) of each 64-row group;
  // global source pre-swizzled so LDS[r][blk] = global k-chunk blk^(r&7).
  const int srow = tid >> 3;                    // 0..63
  const int sblk = (tid & 7) ^ (srow & 7);      // global 16B-chunk
  const bf16* Ag = A + (bM + srow) * (long)K + (sblk << 3);
  const bf16* Bg = Bm + (bN + srow) * (long)K + (sblk << 3);
  const int sdst = srow * 64 + ((tid & 7) << 3);  // elems; = uniform + lane*8

  auto stA = [&](int kt, int sb, int i) {
    gload_lds16(Ag + (long)i * 64 * K + kt * 64, &As[sb][sdst + i * 64 * 64]);
  };
  auto stB = [&](int kt, int sb, int i) {
    gload_lds16(Bg + (long)i * 64 * K + kt * 64, &Bs[sb][sdst + i * 64 * 64]);
  };
  // Frag reads: global k-chunk (kk*4+quad) at row r lives in blk^(r&7);
  // row&7 == fr&7 (base rows are multiples of 16). Bank-exact: conflict-free.
  auto rdA = [&](int rb, int mi, int kk) {
    int row = wr * (BM / 2) + mi * 16 + fr;
    return *(const bf16x8*)&As[rb][row * 64 + (((kk * 4 + quad) ^ (fr & 7)) << 3)];
  };
  auto rdB = [&](int rb, int ni, int kk) {
    int row = wc * 64 + ni * 16 + fr;
    return *(const bf16x8*)&Bs[rb][row * 64 + (((kk * 4 + quad) ^ (fr & 7)) << 3)];
  };

  // Prologue: tile 0 -> buf 0, full drain.
#pragma unroll
  for (int i = 0; i < NA; i++) stA(0, 0, i);
#pragma unroll
  for (int i = 0; i < 4; i++) stB(0, 0, i);
  __syncthreads();

  const int NT = K >> 6;
  for (int kt = 0; kt < NT; ++kt) {
    const int rb = kt & 1, sb = rb ^ 1;
    const bool st = (kt + 1) < NT;
    bf16x8 bfv[4][2], ah[MR2][2];

    // ---- phase 0: read B-all + A-half0; stage; MFMA (mh0, ni 0..1)
#pragma unroll
    for (int ni = 0; ni < 4; ni++)
#pragma unroll
      for (int kk = 0; kk < 2; kk++) bfv[ni][kk] = rdB(rb, ni, kk);
#pragma unroll
    for (int mi = 0; mi < MR2; mi++)
#pragma unroll
      for (int kk = 0; kk < 2; kk++) ah[mi][kk] = rdA(rb, mi, kk);
    if (st) {
      if (BM == 256) { stA(kt + 1, sb, 0); stA(kt + 1, sb, 1); }
      else { stA(kt + 1, sb, 0); stB(kt + 1, sb, 0); }
    }
    __builtin_amdgcn_s_barrier();
    __builtin_amdgcn_s_setprio(1);
#pragma unroll
    for (int mi = 0; mi < MR2; mi++)
#pragma unroll
      for (int ni = 0; ni < 2; ni++)
#pragma unroll
        for (int kk = 0; kk < 2; kk++) acc[mi][ni] = MFMA(ah[mi][kk], bfv[ni][kk], acc[mi][ni]);
    __builtin_amdgcn_s_setprio(0);
    __builtin_amdgcn_s_barrier();

    // ---- phase 1: stage; MFMA (mh0, ni 2..3)
    if (st) {
      if (BM == 256) { stA(kt + 1, sb, 2); stA(kt + 1, sb, 3); }
      else { stA(kt + 1, sb, 1); stB(kt + 1, sb, 1); }
    }
    __builtin_amdgcn_s_barrier();
    __builtin_amdgcn_s_setprio(1);
#pragma unroll
    for (int mi = 0; mi < MR2; mi++)
#pragma unroll
      for (int ni = 2; ni < 4; ni++)
#pragma unroll
        for (int kk = 0; kk < 2; kk++) acc[mi][ni] = MFMA(ah[mi][kk], bfv[ni][kk], acc[mi][ni]);
    __builtin_amdgcn_s_setprio(0);
    __builtin_amdgcn_s_barrier();

    // ---- phase 2: read A-half1; stage; MFMA (mh1, ni 0..1)
#pragma unroll
    for (int mi = 0; mi < MR2; mi++)
#pragma unroll
      for (int kk = 0; kk < 2; kk++) ah[mi][kk] = rdA(rb, mi + MR2, kk);
    if (st) {
      if (BM == 256) { stB(kt + 1, sb, 0); stB(kt + 1, sb, 1); }
      else { stB(kt + 1, sb, 2); }
    }
    __builtin_amdgcn_s_barrier();
    __builtin_amdgcn_s_setprio(1);
#pragma unroll
    for (int mi = 0; mi < MR2; mi++)
#pragma unroll
      for (int ni = 0; ni < 2; ni++)
#pragma unroll
        for (int kk = 0; kk < 2; kk++)
          acc[mi + MR2][ni] = MFMA(ah[mi][kk], bfv[ni][kk], acc[mi + MR2][ni]);
    __builtin_amdgcn_s_setprio(0);
    __builtin_amdgcn_s_barrier();

    // ---- phase 3: stage; MFMA (mh1, ni 2..3); tile-end drain barrier
    if (st) {
      if (BM == 256) { stB(kt + 1, sb, 2); stB(kt + 1, sb, 3); }
      else { stB(kt + 1, sb, 3); }
    }
    __builtin_amdgcn_s_barrier();
    __builtin_amdgcn_s_setprio(1);
#pragma unroll
    for (int mi = 0; mi < MR2; mi++)
#pragma unroll
      for (int ni = 2; ni < 4; ni++)
#pragma unroll
        for (int kk = 0; kk < 2; kk++)
          acc[mi + MR2][ni] = MFMA(ah[mi][kk], bfv[ni][kk], acc[mi + MR2][ni]);
    __builtin_amdgcn_s_setprio(0);
    __syncthreads();  // vmcnt+lgkm drain: publishes staged buf, releases rb
  }

  // Epilogue
#pragma unroll
  for (int mi = 0; mi < MR; mi++)
#pragma unroll
    for (int ni = 0; ni < 4; ni++)
#pragma unroll
      for (int r = 0; r < 4; r++) {
        long row = bM + wr * (BM / 2) + mi * 16 + quad * 4 + r;
        long col = bN + wc * 64 + ni * 16 + fr;
        float v = acc[mi][ni][r];
        if (MODE == 2) {
          Cf[row * (long)N + col] = v;
        } else {
          if (gsel)
            C2[row * (long)N + col] = (bf16)fast_silu(v);
          else
            C1[row * (long)N + col] = (bf16)(v * 11.3137085f);  // sqrt(dk)
        }
      }
}

// ---------------------------------------------------------------------------
// Fused attention v2: 64 Q-rows x 32-row K-tiles, 512 threads (8 waves),
// MAX-OCCUPANCY (4 blocks/CU = 32 waves/CU = 8/SIMD; launch_bounds(512,8)
// caps VGPR at 64 — current kernel already achieves 64 with 2x the state)
// + SOFTWARE-PIPELINED PV: iter t = { stage K(t+1),V(t); S^T(t); PV(t-1);
// silu->Ps[cur]; vmcnt(0)+lgkm(0)+barrier } — ONE barrier/iter, silu of
// tile t overlaps PV MFMAs of t-1, staged loads get a full iteration of
// flight. Buffer rotation (all parity-disjoint, audited):
//   K(t+1)->Ks[(t+1)&1] vs S^T reads Ks[t&1];
//   V(t)->Vts[t&1]      vs PV(t-1) reads Vts[(t-1)&1];
//   silu->Ps[t&1]       vs PV(t-1) reads Ps[(t-1)&1].
// LDS 40KB: Ks 2x8KB [32][128] chunk^=(row&15); Vts 2x8KB [128][32] and
// Ps 2x4KB [64][32] with 8B-block^=(row&6) (even XOR keeps 16B reads
// contiguous; staging pre-swizzles the GLOBAL address — rule 21).
// S^T: wave m16 x n16 (2m x 4n); PV: wave n16 x dv64 (4n x 2dv).
// Grid 1024: h = ((bid&7)<<1)|(bid>>9) — 2 heads/XCD, K/V panels (4MB) L2.
// ---------------------------------------------------------------------------
__global__ __launch_bounds__(512, 8) void attn_fused(const bf16* __restrict__ q,
                                                     const bf16* __restrict__ kw,
                                                     const bf16* __restrict__ vt,
                                                     bf16* __restrict__ gate_io) {
  constexpr int E = 2048, M = 4096, NT = 128;  // 128 tiles of 32 K-rows
  constexpr float scale = 11.3137085f;         // sqrt(dv) folded out of V
  const int bid = blockIdx.x;
  const int h = ((bid & 7) << 1) | (bid >> 9);
  const int sub = (bid >> 3) & 63;
  const long n0 = (long)(sub >> 5) * 2048 + (sub & 31) * 64;

  const int tid = threadIdx.x, wave = tid >> 6, lane = tid & 63;
  const int quad = lane >> 4, ln = lane & 15;
  const int sw_m = wave & 1, sw_n = wave >> 1;   // S^T: m16 x n16 (2m x 4n)
  const int pw_n = wave & 3, pw_dv = wave >> 2;  // PV:  n16 x dv64 (4n x 2dv)

  __shared__ bf16 Ks[2][32 * 128];
  __shared__ bf16 Vts[2][128 * 32];
  __shared__ bf16 Ps[2][64 * 32];

  // Q B-fragments: n16 x dk128 per wave (q pre-scaled by sqrt(dk))
  const bf16* qb = q + (n0 + sw_n * 16 + ln) * E + h * 128 + (quad << 3);
  bf16x8 qf[4];
#pragma unroll
  for (int ks = 0; ks < 4; ks++) qf[ks] = *(const bf16x8*)(qb + ks * 32);

  f32x4 oacc[4] = {};

  // Staging (1 gload_lds/thread/tile each; LDS dst byte = tid*16, linear):
  // K: thread row=tid>>4, chunk c=tid&15 holds global chunk c^(row&15).
  const bf16* kg = kw + (long)(tid >> 4) * E + h * 128 +
                   (((tid & 15) ^ ((tid >> 4) & 15)) << 3);
  // V: thread row dv=tid>>2, 16B-chunk c=tid&3 holds global chunk
  // c^((dv>>1)&3) = c^((tid>>3)&3).
  const bf16* vg = vt + (long)(h * 128 + (tid >> 2)) * M +
                   (((tid & 3) ^ ((tid >> 3) & 3)) << 3);
  const int ldst = tid * 8;  // elems

  // Hoisted LDS offsets (elems)
  int aoff[4];
#pragma unroll
  for (int ks = 0; ks < 4; ks++)
    aoff[ks] = (sw_m * 16 + ln) * 128 + (((ks * 4 + quad) ^ ln) << 3);
  const int pwr = (sw_n * 16 + ln) * 32 + (((sw_m * 4 + quad) ^ (ln & 6)) << 2);
  const int prd = (pw_n * 16 + ln) * 32 + ((quad ^ ((ln >> 1) & 3)) << 3);
  int voff[4];
#pragma unroll
  for (int dt = 0; dt < 4; dt++)
    voff[dt] = (pw_dv * 64 + dt * 16 + ln) * 32 + ((quad ^ ((ln >> 1) & 3)) << 3);

  // Prologue: K(0) only (V(0) staged in iter 0, first used by PV(0) in iter 1)
  gload_lds16(kg, &Ks[0][ldst]);
  asm volatile("s_waitcnt vmcnt(0)" ::: "memory");
  __builtin_amdgcn_s_barrier();

  for (int t = 0; t < NT; ++t) {
    const int cur = t & 1, prv = cur ^ 1;
    if (t + 1 < NT) gload_lds16(kg + (long)(t + 1) * 32 * E, &Ks[prv][ldst]);
    gload_lds16(vg + t * 32, &Vts[cur][ldst]);

    // ---- S^T(t): wave m16 x n16, 4 MFMA ----
    f32x4 sacc = {};
    __builtin_amdgcn_s_setprio(1);
#pragma unroll
    for (int ks = 0; ks < 4; ks++) {
      bf16x8 af = *(const bf16x8*)&Ks[cur][aoff[ks]];
      sacc = MFMA(af, qf[ks], sacc);
    }
    __builtin_amdgcn_s_setprio(0);

    // ---- PV(t-1): wave n16 x dv64, 4 MFMA (overlaps silu below) ----
    if (t > 0) {
      bf16x8 pf = *(const bf16x8*)&Ps[prv][prd];
      __builtin_amdgcn_s_setprio(1);
#pragma unroll
      for (int dt = 0; dt < 4; dt++) {
        bf16x8 vf = *(const bf16x8*)&Vts[prv][voff[dt]];
        oacc[dt] = MFMA(pf, vf, oacc[dt]);
      }
      __builtin_amdgcn_s_setprio(0);
    }

    // ---- silu(S^T(t)) -> Ps[cur] (one ds_write_b64) ----
    bf16x4 p;
#pragma unroll
    for (int r = 0; r < 4; r++) p[r] = (bf16)fast_silu(sacc[r]);
    *(bf16x4*)&Ps[cur][pwr] = p;

    // One barrier/iter: staged loads (full-iter flight) + LDS writes publish.
    asm volatile("s_waitcnt vmcnt(0) lgkmcnt(0)" ::: "memory");
    __builtin_amdgcn_s_barrier();
  }

  // Tail: PV(NT-1)
  {
    constexpr int prv = (NT - 1) & 1;
    bf16x8 pf = *(const bf16x8*)&Ps[prv][prd];
#pragma unroll
    for (int dt = 0; dt < 4; dt++) {
      bf16x8 vf = *(const bf16x8*)&Vts[prv][voff[dt]];
      oacc[dt] = MFMA(pf, vf, oacc[dt]);
    }
  }

  // Epilogue: gated = gate * (O * scale); gate_io aliases glin/gated
  bf16* gio = gate_io + n0 * E + h * 128;
#pragma unroll
  for (int dt = 0; dt < 4; dt++)
#pragma unroll
    for (int r = 0; r < 4; r++) {
      int n = pw_n * 16 + quad * 4 + r;
      int dv = pw_dv * 64 + dt * 16 + ln;
      float g = (float)gio[(long)n * E + dv];
      gio[(long)n * E + dv] = (bf16)(g * oacc[dt][r] * scale);
    }
}

// ---------------------------------------------------------------------------
extern "C" void kernel_launch(void* const* d_in, const int* in_sizes, int n_in,
                              void* d_out, int out_size, void* d_ws, size_t ws_size,
                              hipStream_t stream) {
  const float* x = (const float*)d_in[0];
  const float* Wq = (const float*)d_in[1];
  const float* kw = (const float*)d_in[2];
  const float* vw = (const float*)d_in[3];
  const float* Wg = (const float*)d_in[4];
  const float* Wout = (const float*)d_in[5];
  float* out = (float*)d_out;
  bf16* ws = (bf16*)d_ws;

  // 5 slots x 8,388,608 bf16 = 83.9 MB
  bf16* S0 = ws;              // xb, then kwb
  bf16* S1 = ws + 8388608;    // Wqb | Wgb, then Woutb
  bf16* S2 = ws + 16777216;   // vt
  bf16* S3 = ws + 25165824;   // q (pre-scaled)
  bf16* S4 = ws + 33554432;   // glin (silu'd) -> gated in-place
  bf16* Wgb = S1 + 4194304;

  cvt_bf16<<<8192, 256, 0, stream>>>(x, S0, 8388608);
  cvt_bf16<<<4096, 256, 0, stream>>>(Wq, S1, 4194304);
  cvt_bf16<<<4096, 256, 0, stream>>>(Wg, Wgb, 4194304);
  transpose_v_cvt<<<dim3(64, 32), 256, 0, stream>>>(vw, S2);
  // q = qscale*(x Wq^T); glin = silu(x Wg^T)  — one dual GEMM, 256x256 tiles
  gemm256<3, 256><<<256, 512, 0, stream>>>(S0, S1, Wgb, S3, S4, (float*)nullptr, 2048, 2048);
  cvt_bf16<<<8192, 256, 0, stream>>>(kw, S0, 8388608);  // xb dead -> kwb
  // gated = glin * scale * (silu(q K^T) V), in-place on S4
  attn_fused<<<1024, 512, 0, stream>>>(S3, S0, S2, S4);
  cvt_bf16<<<4096, 256, 0, stream>>>(Wout, S1, 4194304);  // Wq/Wg dead -> Woutb
  // out = gated Wout^T (fp32), 128x256 tiles
  gemm256<2, 128><<<256, 512, 0, stream>>>(S4, S1, (const bf16*)nullptr, (bf16*)nullptr,
                                           (bf16*)nullptr, out, 2048, 2048);
}

// Round 9
// 440.647 us; speedup vs baseline: 1.1322x; 1.1322x over previous
//
#include <hip/hip_runtime.h>

typedef __bf16 bf16;
typedef __bf16 bf16x4 __attribute__((ext_vector_type(4)));
typedef __bf16 bf16x8 __attribute__((ext_vector_type(8)));
typedef float f32x4 __attribute__((ext_vector_type(4)));

#define MFMA(a, b, c) __builtin_amdgcn_mfma_f32_16x16x32_bf16(a, b, c, 0, 0, 0)

__device__ __forceinline__ float fast_silu(float x) {
  float e = __builtin_amdgcn_exp2f(x * -1.4426950408889634f);
  return x * __builtin_amdgcn_rcpf(1.f + e);
}

// async global->LDS, 16B/lane. LDS dest must be wave-uniform base + lane*16;
// all swizzling goes on the GLOBAL address.
__device__ __forceinline__ void gload_lds16(const void* g, void* l) {
  __builtin_amdgcn_global_load_lds(
      (const __attribute__((address_space(1))) void*)g,
      (__attribute__((address_space(3))) void*)l, 16, 0, 0);
}

__device__ __forceinline__ void cvt4(const float* __restrict__ in,
                                     bf16* __restrict__ out, int i) {
  float4 v = *(const float4*)(in + i);
  bf16x4 o = {(bf16)v.x, (bf16)v.y, (bf16)v.z, (bf16)v.w};
  *(bf16x4*)(out + i) = o;
}

// ---------------------------------------------------------------------------
// prep1: x/Wq/Wg fp32->bf16 + V transpose-cvt, ONE launch (was 4).
// blocks: [0,8192) x | [8192,12288) Wq | [12288,16384) Wg | [16384,18432) vt.
// ---------------------------------------------------------------------------
__global__ __launch_bounds__(256) void prep1(const float* __restrict__ x,
                                             const float* __restrict__ Wq,
                                             const float* __restrict__ Wg,
                                             const float* __restrict__ vw,
                                             bf16* __restrict__ xb,
                                             bf16* __restrict__ Wqb,
                                             bf16* __restrict__ Wgb,
                                             bf16* __restrict__ vt) {
  __shared__ bf16 T[64 * 72];
  const int b = blockIdx.x, tid = threadIdx.x;
  if (b < 8192) {
    cvt4(x, xb, (b * 256 + tid) * 4);
  } else if (b < 12288) {
    cvt4(Wq, Wqb, ((b - 8192) * 256 + tid) * 4);
  } else if (b < 16384) {
    cvt4(Wg, Wgb, ((b - 12288) * 256 + tid) * 4);
  } else {
    // v_weight [4096,2048] fp32 -> vt [2048,4096] bf16 (vt[hd][m] = v[m][hd])
    const int bid2 = b - 16384;
    const int m0 = (bid2 & 63) * 64, c0 = (bid2 >> 6) * 64;
    const int tr = tid >> 3;        // 0..31
    const int tc = (tid & 7) << 3;  // 0..56
#pragma unroll
    for (int it = 0; it < 2; it++) {
      int r = tr + it * 32;
      const float* src = vw + (long)(m0 + r) * 2048 + c0 + tc;
      float4 a = *(const float4*)src;
      float4 bb = *(const float4*)(src + 4);
      bf16x8 t = {(bf16)a.x, (bf16)a.y, (bf16)a.z, (bf16)a.w,
                  (bf16)bb.x, (bf16)bb.y, (bf16)bb.z, (bf16)bb.w};
      *(bf16x8*)&T[r * 72 + tc] = t;
    }
    __syncthreads();
#pragma unroll
    for (int it = 0; it < 2; it++) {
      int c = tr + it * 32;
      bf16x8 o;
#pragma unroll
      for (int j = 0; j < 8; j++) o[j] = T[(tc + j) * 72 + c];
      *(bf16x8*)(vt + (long)(c0 + c) * 4096 + m0 + tc) = o;
    }
  }
}

// prep2: kw/Wout fp32->bf16 (after GEMM1 frees S0/S1). blocks:
// [0,8192) kw | [8192,12288) Wout.
__global__ __launch_bounds__(256) void prep2(const float* __restrict__ kw,
                                             const float* __restrict__ Wout,
                                             bf16* __restrict__ kwb,
                                             bf16* __restrict__ Woutb) {
  const int b = blockIdx.x, tid = threadIdx.x;
  if (b < 8192)
    cvt4(kw, kwb, (b * 256 + tid) * 4);
  else
    cvt4(Wout, Woutb, ((b - 8192) * 256 + tid) * 4);
}

// ---------------------------------------------------------------------------
// NT GEMM, BM x 256 tile, BK=64, 512 threads (8 waves, 2M x 4N), 4 phases
// per K-tile. COUNTED-vmcnt + PER-PHASE stage interleave (the combination
// rounds 5/6 each tested half of):
//   A triple-buffered, staged 2 K-tiles ahead; B double-buffered, 1 ahead.
//   Stage spread 2 gloads/phase: ph0/ph1 = B(kt+1) halves, ph2/ph3 =
//   A(kt+2) halves. Tile-end s_waitcnt vmcnt(NA) retires exactly
//   A(kt+1)+B(kt+1) (in-order vmcnt), keeps A(kt+2) airborne. Never
//   vmcnt(0) in the main loop (m218: counted wait IS the phase gain;
//   m196: interleave without counted, or counted without interleave, both
//   lose).
//   Invariant: entering kt, outstanding = A(kt+1) x NA. End of kt:
//   NA + 4 + NA outstanding -> vmcnt(NA). Prologue establishes it.
// LDS [row][64] bf16, 16B-chunk swizzle blk^=row&7; pre-swizzled global
// source for the linear gload_lds dest (rule 21); reads bank-exact
// conflict-free. MODE3 BM=256: LDS 3x32+2x32 = 160KB. MODE2 BM=128: 112KB.
// Tail stages clamp the source tile (uniform instr count keeps vmcnt
// constants valid; clamped writes land in dead buffers).
// MODE 3: dual-output, gx<8 -> C1 = qscale*(A B^T), gx>=8 -> C2 =
//   silu(A B2^T). MODE 2: Cf = A B^T fp32. Grid 256, XCD-bijective swizzle.
// ---------------------------------------------------------------------------
template <int MODE, int BM>
__global__ __launch_bounds__(512, 2) void gemm256(const bf16* __restrict__ A,
                                                  const bf16* __restrict__ B,
                                                  const bf16* __restrict__ B2,
                                                  bf16* __restrict__ C1,
                                                  bf16* __restrict__ C2,
                                                  float* __restrict__ Cf, int K, int N) {
  constexpr int MR = BM / 32;  // 16-row A-frags per wave
  constexpr int MR2 = MR / 2;
  constexpr int NA = BM / 64;  // A gload_lds per K-tile (4 or 2)
  __shared__ bf16 As[3][BM * 64];
  __shared__ bf16 Bs[2][256 * 64];

  const int tid = threadIdx.x, wave = tid >> 6, lane = tid & 63;
  const int wr = wave >> 2, wc = wave & 3;
  const int quad = lane >> 4, fr = lane & 15;

  // XCD-bijective swizzle: 32 consecutive ids (one XCD) share one B-panel.
  const int id2 = (blockIdx.x & 7) * 32 + (blockIdx.x >> 3);
  const int gx = (MODE == 3) ? (id2 >> 4) : (id2 >> 5);
  const int gy = (MODE == 3) ? (id2 & 15) : (id2 & 31);
  const bool gsel = (MODE == 3) && (gx >= 8);
  const bf16* Bm = gsel ? B2 : B;
  const long bM = (long)gy * BM;
  const long bN = (long)((MODE == 3) ? (gx & 7) : gx) * 256;

  f32x4 acc[MR][4] = {};

  // Staging: thread t writes LDS bytes [t*16,+16) of each 64-row group;
  // global source pre-swizzled so LDS[r][blk] = global k-chunk blk^(r&7).
  const int srow = tid >> 3;                // 0..63
  const int sblk = (tid & 7) ^ (srow & 7);  // global 16B-chunk
  const bf16* Ag = A + (bM + srow) * (long)K + (sblk << 3);
  const bf16* Bg = Bm + (bN + srow) * (long)K + (sblk << 3);
  const int sdst = srow * 64 + ((tid & 7) << 3);  // elems; uniform + lane*8

  auto stA = [&](int kt, int sb, int i) {
    gload_lds16(Ag + (long)i * 64 * K + kt * 64, &As[sb][sdst + i * 64 * 64]);
  };
  auto stB = [&](int kt, int sb, int i) {
    gload_lds16(Bg + (long)i * 64 * K + kt * 64, &Bs[sb][sdst + i * 64 * 64]);
  };
  // Frag reads: global k-chunk (kk*4+quad) at row r lives in blk^(r&7);
  // row&7 == fr&7 (base rows are multiples of 16). Bank-exact conflict-free.
  auto rdA = [&](int ab, int mi, int kk) {
    int row = wr * (BM / 2) + mi * 16 + fr;
    return *(const bf16x8*)&As[ab][row * 64 + (((kk * 4 + quad) ^ (fr & 7)) << 3)];
  };
  auto rdB = [&](int bb, int ni, int kk) {
    int row = wc * 64 + ni * 16 + fr;
    return *(const bf16x8*)&Bs[bb][row * 64 + (((kk * 4 + quad) ^ (fr & 7)) << 3)];
  };

  const int NT = K >> 6;
  // Prologue: B(0), A(0), A(1) — establish "A(kt+1) in flight" invariant.
#pragma unroll
  for (int i = 0; i < 4; i++) stB(0, 0, i);
#pragma unroll
  for (int i = 0; i < NA; i++) stA(0, 0, i);
#pragma unroll
  for (int i = 0; i < NA; i++) stA(NT > 1 ? 1 : 0, 1, i);
  if constexpr (NA == 4)
    asm volatile("s_waitcnt vmcnt(4)" ::: "memory");
  else
    asm volatile("s_waitcnt vmcnt(2)" ::: "memory");
  __builtin_amdgcn_s_barrier();

  for (int kt = 0; kt < NT; ++kt) {
    const int ra = kt % 3, rb = kt & 1;
    const int ktB = kt + 1 < NT ? kt + 1 : NT - 1, bb = (kt + 1) & 1;
    const int ktA = kt + 2 < NT ? kt + 2 : NT - 1, ab2 = (kt + 2) % 3;
    bf16x8 bfv[4][2], ah[MR2][2];

    // ---- phase 0: read B-all + A-half0; stage B(kt+1) half0; MFMA q(0,0)
#pragma unroll
    for (int ni = 0; ni < 4; ni++)
#pragma unroll
      for (int kk = 0; kk < 2; kk++) bfv[ni][kk] = rdB(rb, ni, kk);
#pragma unroll
    for (int mi = 0; mi < MR2; mi++)
#pragma unroll
      for (int kk = 0; kk < 2; kk++) ah[mi][kk] = rdA(ra, mi, kk);
    stB(ktB, bb, 0);
    stB(ktB, bb, 1);
    __builtin_amdgcn_s_barrier();
    __builtin_amdgcn_s_setprio(1);
#pragma unroll
    for (int mi = 0; mi < MR2; mi++)
#pragma unroll
      for (int ni = 0; ni < 2; ni++)
#pragma unroll
        for (int kk = 0; kk < 2; kk++) acc[mi][ni] = MFMA(ah[mi][kk], bfv[ni][kk], acc[mi][ni]);
    __builtin_amdgcn_s_setprio(0);
    __builtin_amdgcn_s_barrier();

    // ---- phase 1: stage B(kt+1) half1; MFMA q(0,1)
    stB(ktB, bb, 2);
    stB(ktB, bb, 3);
    __builtin_amdgcn_s_barrier();
    __builtin_amdgcn_s_setprio(1);
#pragma unroll
    for (int mi = 0; mi < MR2; mi++)
#pragma unroll
      for (int ni = 2; ni < 4; ni++)
#pragma unroll
        for (int kk = 0; kk < 2; kk++) acc[mi][ni] = MFMA(ah[mi][kk], bfv[ni][kk], acc[mi][ni]);
    __builtin_amdgcn_s_setprio(0);
    __builtin_amdgcn_s_barrier();

    // ---- phase 2: read A-half1; stage A(kt+2) half0; MFMA q(1,0)
#pragma unroll
    for (int mi = 0; mi < MR2; mi++)
#pragma unroll
      for (int kk = 0; kk < 2; kk++) ah[mi][kk] = rdA(ra, mi + MR2, kk);
    stA(ktA, ab2, 0);
    if constexpr (NA == 4) stA(ktA, ab2, 1);
    else stA(ktA, ab2, 1);
    __builtin_amdgcn_s_barrier();
    __builtin_amdgcn_s_setprio(1);
#pragma unroll
    for (int mi = 0; mi < MR2; mi++)
#pragma unroll
      for (int ni = 0; ni < 2; ni++)
#pragma unroll
        for (int kk = 0; kk < 2; kk++)
          acc[mi + MR2][ni] = MFMA(ah[mi][kk], bfv[ni][kk], acc[mi + MR2][ni]);
    __builtin_amdgcn_s_setprio(0);
    __builtin_amdgcn_s_barrier();

    // ---- phase 3: stage A(kt+2) half1 (MODE3 only); MFMA q(1,1);
    //      COUNTED tile-end wait: only A(kt+2)'s NA loads may stay in flight.
    if constexpr (NA == 4) {
      stA(ktA, ab2, 2);
      stA(ktA, ab2, 3);
    }
    __builtin_amdgcn_s_barrier();
    __builtin_amdgcn_s_setprio(1);
#pragma unroll
    for (int mi = 0; mi < MR2; mi++)
#pragma unroll
      for (int ni = 2; ni < 4; ni++)
#pragma unroll
        for (int kk = 0; kk < 2; kk++)
          acc[mi + MR2][ni] = MFMA(ah[mi][kk], bfv[ni][kk], acc[mi + MR2][ni]);
    __builtin_amdgcn_s_setprio(0);
    if constexpr (NA == 4)
      asm volatile("s_waitcnt vmcnt(4)" ::: "memory");
    else
      asm volatile("s_waitcnt vmcnt(2)" ::: "memory");
    __builtin_amdgcn_s_barrier();
  }

  // Epilogue
#pragma unroll
  for (int mi = 0; mi < MR; mi++)
#pragma unroll
    for (int ni = 0; ni < 4; ni++)
#pragma unroll
      for (int r = 0; r < 4; r++) {
        long row = bM + wr * (BM / 2) + mi * 16 + quad * 4 + r;
        long col = bN + wc * 64 + ni * 16 + fr;
        float v = acc[mi][ni][r];
        if (MODE == 2) {
          Cf[row * (long)N + col] = v;
        } else {
          if (gsel)
            C2[row * (long)N + col] = (bf16)fast_silu(v);
          else
            C1[row * (long)N + col] = (bf16)(v * 11.3137085f);  // sqrt(dk)
        }
      }
}

// ---------------------------------------------------------------------------
// Fused attention (round-2 measured-best: 178-181us), S^T formulation,
// 128 Q-rows per block, 512 THREADS (8 waves).
//   S^T[m64][n128] = K·q^T  (K from LDS as A, Q in regs as B; wave m32 x n32)
//   P = silu(S^T) packed (4 m-consecutive) -> Ps[n][m] via ds_write_b64
//   O[n128][dv128] += P·V^T (wave n32 x dv64, K=32 MFMA)
// Epilogue: gated = gate * O * scale (gate = pre-silu'd glin, in-place RMW).
// 8 waves/block x 2 blocks/CU = 16 waves/CU (4/SIMD). Double-buffered K/V
// staging, counted waits: raw s_barrier mid-iteration (lgkmcnt(0) only —
// staged loads stay in flight), single vmcnt(0) at iteration end. setprio(1)
// around MFMA clusters.
// LDS: Ks 2x16KB + Vts 2x16KB + Ps 16KB = 80KB -> exactly 2 blocks/CU (160KB).
// Swizzles (16B blocks): Ks blk^=m&15, Vts blk^=dv&7, Ps blk^=n&7.
// Grid 512 flat, XCD-grouped (2 heads/XCD -> K/V in per-XCD L2).
// ---------------------------------------------------------------------------
__global__ __launch_bounds__(512, 4) void attn_fused(const bf16* __restrict__ q,
                                                     const bf16* __restrict__ kw,
                                                     const bf16* __restrict__ vt,
                                                     bf16* __restrict__ gate_io) {
  constexpr int E = 2048, M = 4096;
  constexpr float scale = 11.3137085f;  // sqrt(dv) folded out of V
  const int bid = blockIdx.x;
  const int h = ((bid & 7) << 1) | ((bid >> 8) & 1);
  const int sub = (bid >> 3) & 31;
  const int b = sub >> 4, nt = sub & 15;
  const long n0 = (long)b * 2048 + nt * 128;

  const int tid = threadIdx.x, wave = tid >> 6, lane = tid & 63;
  const int quad = lane >> 4, ln = lane & 15;
  const int sw_m = wave & 1, sw_n = wave >> 1;   // S^T: 2m x 4n -> m32 x n32/wave
  const int pw_n = wave & 3, pw_dv = wave >> 2;  // PV:  4n x 2dv -> n32 x dv64/wave

  __shared__ bf16 Ks[2][64 * 128];
  __shared__ bf16 Vts[2][128 * 64];
  __shared__ bf16 Ps[128 * 64];

  // Q B-fragments: n32 x dk128 per wave (pre-scaled by sqrt(dk))
  const bf16* qbase = q + (n0 + sw_n * 32) * E + h * 128;
  bf16x8 qf[2][4];
#pragma unroll
  for (int n2 = 0; n2 < 2; n2++)
#pragma unroll
    for (int ks = 0; ks < 4; ks++)
      qf[n2][ks] = *(const bf16x8*)(qbase + (long)(n2 * 16 + ln) * E + ks * 32 + (quad << 3));

  f32x4 oacc[2][4] = {};

  // K staging: wave rows [wave*8,+8), 2 instrs of 4 rows
  const bf16* kg = kw + (long)((wave << 3) + quad) * E + h * 128;
  const int ksl_off = (wave << 3) * 128 + lane * 8;
  int kc[2];
#pragma unroll
  for (int i = 0; i < 2; i++) kc[i] = (ln ^ ((wave * 8 + i * 4 + quad) & 15)) << 3;

  // V staging: wave dv-rows [wave*16,+16), 2 instrs of 8 rows
  const bf16* vg = vt + (long)(h * 128 + (wave << 4) + (lane >> 3)) * M +
                   (((lane & 7) ^ ((lane >> 3) & 7)) << 3);
  const int vsl_off = (wave << 4) * 64 + lane * 8;

  // P-write addresses (4, hoisted): tiles (mt, n2)
  int waddr[2][2];
#pragma unroll
  for (int mt = 0; mt < 2; mt++)
#pragma unroll
    for (int n2 = 0; n2 < 2; n2++) {
      int n = sw_n * 32 + n2 * 16 + ln;
      int mb8 = sw_m * 4 + mt * 2 + (quad >> 1);
      waddr[mt][n2] = n * 64 + ((mb8 ^ (n & 7)) << 3) + ((quad & 1) << 2);
    }

  auto stage = [&](int ms, int sb) {
#pragma unroll
    for (int i = 0; i < 2; i++) {
      gload_lds16(kg + (long)(ms + i * 4) * E + kc[i], &Ks[sb][ksl_off + i * 4 * 128]);
      gload_lds16(vg + ms + (long)i * 8 * M, &Vts[sb][vsl_off + i * 8 * 64]);
    }
  };

  // Prologue: tile 0 -> buf 0, full drain.
  stage(0, 0);
  asm volatile("s_waitcnt vmcnt(0)" ::: "memory");
  __builtin_amdgcn_s_barrier();

  auto body = [&](int m0, int rb, int sb, bool doStage) {
    // Issue next tile's loads first: they fly across the mid barrier and
    // complete during this iteration's compute.
    if (doStage) stage(m0 + 64, sb);

    // S^T = K · Q^T  (D rows = m, cols = n); wave: m32 x n32
    f32x4 sacc[2][2] = {};
    __builtin_amdgcn_s_setprio(1);
#pragma unroll
    for (int ks = 0; ks < 4; ks++) {
      bf16x8 af[2];
#pragma unroll
      for (int mt = 0; mt < 2; mt++)
        af[mt] = *(const bf16x8*)&Ks[rb][(sw_m * 32 + mt * 16 + ln) * 128 +
                                         (((ks * 4 + quad) ^ ln) << 3)];
#pragma unroll
      for (int mt = 0; mt < 2; mt++)
#pragma unroll
        for (int n2 = 0; n2 < 2; n2++) sacc[mt][n2] = MFMA(af[mt], qf[n2][ks], sacc[mt][n2]);
    }
    __builtin_amdgcn_s_setprio(0);

    // silu + pack 4 m-consecutive values -> one ds_write_b64 per tile
#pragma unroll
    for (int mt = 0; mt < 2; mt++)
#pragma unroll
      for (int n2 = 0; n2 < 2; n2++) {
        bf16x4 p;
#pragma unroll
        for (int r = 0; r < 4; r++) p[r] = (bf16)fast_silu(sacc[mt][n2][r]);
        *(bf16x4*)&Ps[waddr[mt][n2]] = p;
      }

    // Ps visibility barrier: drain LDS only — staged loads stay in flight.
    asm volatile("s_waitcnt lgkmcnt(0)" ::: "memory");
    __builtin_amdgcn_s_barrier();

    // O += P · V^T; wave: n32 x dv64
#pragma unroll
    for (int ks = 0; ks < 2; ks++) {
      const int so = ((ks * 4 + quad) ^ (ln & 7)) << 3;
      bf16x8 pf[2], vf[4];
#pragma unroll
      for (int n2 = 0; n2 < 2; n2++)
        pf[n2] = *(const bf16x8*)&Ps[(pw_n * 32 + n2 * 16 + ln) * 64 + so];
#pragma unroll
      for (int dt = 0; dt < 4; dt++)
        vf[dt] = *(const bf16x8*)&Vts[rb][(pw_dv * 64 + dt * 16 + ln) * 64 + so];
      __builtin_amdgcn_s_setprio(1);
#pragma unroll
      for (int n2 = 0; n2 < 2; n2++)
#pragma unroll
        for (int dt = 0; dt < 4; dt++) oacc[n2][dt] = MFMA(pf[n2], vf[dt], oacc[n2][dt]);
      __builtin_amdgcn_s_setprio(0);
    }

    // End-of-iteration: staged loads (issued one full compute phase ago)
    // must be LDS-visible to all waves; also releases buf[rb] for overwrite.
    asm volatile("s_waitcnt vmcnt(0)" ::: "memory");
    __builtin_amdgcn_s_barrier();
  };

  for (int m0 = 0; m0 < M; m0 += 128) {
    body(m0, 0, 1, true);
    body(m0 + 64, 1, 0, m0 + 128 < M);
  }

  // Epilogue: gated = gate * (O * scale); gate_io aliases glin/gated
  bf16* gio = gate_io + n0 * E + h * 128;
#pragma unroll
  for (int n2 = 0; n2 < 2; n2++)
#pragma unroll
    for (int dt = 0; dt < 4; dt++)
#pragma unroll
      for (int r = 0; r < 4; r++) {
        int n = pw_n * 32 + n2 * 16 + quad * 4 + r;
        int dv = pw_dv * 64 + dt * 16 + ln;
        float g = (float)gio[(long)n * E + dv];
        gio[(long)n * E + dv] = (bf16)(g * oacc[n2][dt][r] * scale);
      }
}

// ---------------------------------------------------------------------------
extern "C" void kernel_launch(void* const* d_in, const int* in_sizes, int n_in,
                              void* d_out, int out_size, void* d_ws, size_t ws_size,
                              hipStream_t stream) {
  const float* x = (const float*)d_in[0];
  const float* Wq = (const float*)d_in[1];
  const float* kw = (const float*)d_in[2];
  const float* vw = (const float*)d_in[3];
  const float* Wg = (const float*)d_in[4];
  const float* Wout = (const float*)d_in[5];
  float* out = (float*)d_out;
  bf16* ws = (bf16*)d_ws;

  // 5 slots x 8,388,608 bf16 = 83.9 MB
  bf16* S0 = ws;              // xb, then kwb
  bf16* S1 = ws + 8388608;    // Wqb | Wgb, then Woutb
  bf16* S2 = ws + 16777216;   // vt
  bf16* S3 = ws + 25165824;   // q (pre-scaled)
  bf16* S4 = ws + 33554432;   // glin (silu'd) -> gated in-place
  bf16* Wgb = S1 + 4194304;

  // prep1: xb, Wqb, Wgb, vt in one launch
  prep1<<<18432, 256, 0, stream>>>(x, Wq, Wg, vw, S0, S1, Wgb, S2);
  // q = qscale*(x Wq^T); glin = silu(x Wg^T)  — one dual GEMM, 256x256 tiles
  gemm256<3, 256><<<256, 512, 0, stream>>>(S0, S1, Wgb, S3, S4, (float*)nullptr, 2048, 2048);
  // kwb -> S0 (xb dead), Woutb -> S1 (Wqb/Wgb dead)
  prep2<<<12288, 256, 0, stream>>>(kw, Wout, S0, S1);
  // gated = glin * scale * (silu(q K^T) V), in-place on S4
  attn_fused<<<512, 512, 0, stream>>>(S3, S0, S2, S4);
  // out = gated Wout^T (fp32), 128x256 tiles
  gemm256<2, 128><<<256, 512, 0, stream>>>(S4, S1, (const bf16*)nullptr, (bf16*)nullptr,
                                           (bf16*)nullptr, out, 2048, 2048);
}